// Round 8
// baseline (401.013 us; speedup 1.0000x reference)
//
#include <hip/hip_runtime.h>

typedef __attribute__((ext_vector_type(8))) short bf16x8;
typedef __attribute__((ext_vector_type(4))) short s16x4;
typedef __attribute__((ext_vector_type(4))) float f32x4;

#define NTOK 262144   // 64^3 tokens
#define NWIN 4096     // 16^3 windows of 4^3

__device__ __forceinline__ unsigned short f2bf(float f) {
    unsigned int u = __float_as_uint(f);
    return (unsigned short)((u + 0x7FFFu + ((u >> 16) & 1u)) >> 16);
}
__device__ __forceinline__ float bf2f(unsigned short u) {
    return __uint_as_float(((unsigned int)u) << 16);
}
__device__ __forceinline__ int region(int g) { return (g >= 60) + (g >= 62); }

// ---------------- K0: weight convert + transpose to N-major bf16 ----------------
__global__ void convert_weights(const float* __restrict__ Wqkv, const float* __restrict__ Wout,
                                const float* __restrict__ W1, const float* __restrict__ W2,
                                unsigned short* __restrict__ wq_t, unsigned short* __restrict__ wo_t,
                                unsigned short* __restrict__ w1_t, unsigned short* __restrict__ w2_t) {
    int idx = blockIdx.x * blockDim.x + threadIdx.x;
    if (idx < 27648) {                       // wq_t[288][96] = Wqkv[96][288]^T
        int n = idx / 96, k = idx % 96;
        wq_t[idx] = f2bf(Wqkv[k * 288 + n]);
    } else if (idx < 27648 + 9216) {         // wo_t[96][96]
        int i = idx - 27648; int n = i / 96, k = i % 96;
        wo_t[i] = f2bf(Wout[k * 96 + n]);
    } else if (idx < 27648 + 9216 + 36864) { // w1_t[384][96]
        int i = idx - 36864; int n = i / 96, k = i % 96;
        w1_t[i] = f2bf(W1[k * 384 + n]);
    } else if (idx < 110592) {               // w2_t[96][384]
        int i = idx - 73728; int n = i / 384, k = i % 384;
        w2_t[i] = f2bf(W2[k * 96 + n]);
    }
}

// ---------------- K1: LN1 + cyclic shift(-2) + window-major relayout ----------------
__global__ __launch_bounds__(256) void ln1_shift_kernel(const float* __restrict__ x,
                                                        const float* __restrict__ g,
                                                        const float* __restrict__ b,
                                                        unsigned short* __restrict__ y) {
    int tid = blockIdx.x * blockDim.x + threadIdx.x;
    int token = tid >> 5;          // output (shifted-frame) token
    int lane = tid & 31;
    if (token >= NTOK) return;
    int pz = token & 63, py = (token >> 6) & 63, px = token >> 12;
    int sx = (px + 2) & 63, sy = (py + 2) & 63, sz = (pz + 2) & 63;   // roll(x,-2)
    size_t src = ((size_t)((sx * 64 + sy) * 64 + sz)) * 96;
    float v0 = x[src + lane], v1 = x[src + 32 + lane], v2 = x[src + 64 + lane];
    float s = v0 + v1 + v2;
    float sq = v0 * v0 + v1 * v1 + v2 * v2;
    #pragma unroll
    for (int m = 16; m >= 1; m >>= 1) { s += __shfl_xor(s, m, 32); sq += __shfl_xor(sq, m, 32); }
    float mean = s * (1.0f / 96.0f);
    float var = sq * (1.0f / 96.0f) - mean * mean;
    float rstd = rsqrtf(var + 1e-5f);
    int win = ((px >> 2) * 16 + (py >> 2)) * 16 + (pz >> 2);
    int loc = ((px & 3) * 4 + (py & 3)) * 4 + (pz & 3);
    size_t dst = ((size_t)(win * 64 + loc)) * 96;
    y[dst + lane]      = f2bf((v0 - mean) * rstd * g[lane]      + b[lane]);
    y[dst + 32 + lane] = f2bf((v1 - mean) * rstd * g[lane + 32] + b[lane + 32]);
    y[dst + 64 + lane] = f2bf((v2 - mean) * rstd * g[lane + 64] + b[lane + 64]);
}

// ---------------- K2: FUSED QKV GEMM + attention (one window, 6 waves) ----------------
__global__ __launch_bounds__(384, 4) void qkv_attn_kernel(
    const unsigned short* __restrict__ y,
    const unsigned short* __restrict__ wq_t,
    const float* __restrict__ pos_tab,
    unsigned short* __restrict__ a_out)
{
    __shared__ __align__(16) unsigned short SH[22272];
    __shared__ __align__(16) float posl[344];
    unsigned short* q_s = SH;             // [3][64][40]
    unsigned short* k_s = SH + 7680;      // [3][64][40]
    unsigned short* vT  = SH + 15360;     // [3][32][72]
    unsigned short* P_s = SH;             // [3][64][72]  (aliases q+k after S2)

    int win = blockIdx.x;
    int tid = threadIdx.x;
    int w = tid >> 6, lane = tid & 63, lr = lane & 15, kh = lane >> 4;
    int ix = win >> 8, iy = (win >> 4) & 15, iz = win & 15;

    if (tid < 343) posl[tid] = pos_tab[tid];

    // ---- P1: QKV GEMM (A = y from global, B = wq_t); scatter to q_s/k_s/vT ----
    {
        f32x4 acc3[4][3];
        #pragma unroll
        for (int m = 0; m < 4; ++m)
            #pragma unroll
            for (int n = 0; n < 3; ++n) acc3[m][n] = (f32x4){0.f, 0.f, 0.f, 0.f};
        #pragma unroll
        for (int ks = 0; ks < 3; ++ks) {
            int k0 = ks * 32;
            bf16x8 a[4], bb[3];
            #pragma unroll
            for (int m = 0; m < 4; ++m)
                a[m] = *(const bf16x8*)(y + ((size_t)win * 64 + m * 16 + lr) * 96 + k0 + kh * 8);
            #pragma unroll
            for (int n = 0; n < 3; ++n)
                bb[n] = *(const bf16x8*)(wq_t + (size_t)(w * 48 + n * 16 + lr) * 96 + k0 + kh * 8);
            #pragma unroll
            for (int m = 0; m < 4; ++m)
                #pragma unroll
                for (int n = 0; n < 3; ++n)
                    acc3[m][n] = __builtin_amdgcn_mfma_f32_16x16x32_bf16(a[m], bb[n], acc3[m][n], 0, 0, 0);
        }
        const float scale = 0.17677669529663689f;   // 32^-0.5 folded into Q
        #pragma unroll
        for (int n = 0; n < 3; ++n) {
            int base = w * 48 + n * 16;
            int qq = base / 96, cc0 = base % 96;
            int hh = cc0 >> 5, d0 = cc0 & 31;
            if (qq == 2) {
                #pragma unroll
                for (int m = 0; m < 4; ++m) {
                    s16x4 pv;
                    #pragma unroll
                    for (int r = 0; r < 4; ++r) pv[r] = (short)f2bf(acc3[m][n][r]);
                    *(s16x4*)&vT[(hh * 32 + d0 + lr) * 72 + m * 16 + kh * 4] = pv;
                }
            } else {
                unsigned short* dst = (qq == 0) ? q_s : k_s;
                float sc = (qq == 0) ? scale : 1.0f;
                #pragma unroll
                for (int m = 0; m < 4; ++m)
                    #pragma unroll
                    for (int r = 0; r < 4; ++r) {
                        int tok = m * 16 + kh * 4 + r;
                        dst[(hh * 64 + tok) * 40 + d0 + lr] = f2bf(acc3[m][n][r] * sc);
                    }
            }
        }
    }
    __syncthreads();   // S1: q/k/vT + posl visible

    // ---- P2: QK^T + bias + mask + softmax (2 waves per head) ----
    int h3 = w >> 1, rb = (w & 1) * 32;
    f32x4 sa[2][4];
    {
        bf16x8 aq[2], bk[4];
        #pragma unroll
        for (int mm = 0; mm < 2; ++mm)
            aq[mm] = *(const bf16x8*)&q_s[(h3 * 64 + rb + mm * 16 + lr) * 40 + kh * 8];
        #pragma unroll
        for (int n = 0; n < 4; ++n)
            bk[n] = *(const bf16x8*)&k_s[(h3 * 64 + n * 16 + lr) * 40 + kh * 8];
        #pragma unroll
        for (int mm = 0; mm < 2; ++mm)
            #pragma unroll
            for (int n = 0; n < 4; ++n)
                sa[mm][n] = __builtin_amdgcn_mfma_f32_16x16x32_bf16(aq[mm], bk[n], (f32x4){0.f,0.f,0.f,0.f}, 0, 0, 0);

        int labj[4], jwx[4], jwy[4], jwz[4];
        #pragma unroll
        for (int n = 0; n < 4; ++n) {
            int j = n * 16 + lr;
            jwx[n] = j >> 4; jwy[n] = (j >> 2) & 3; jwz[n] = j & 3;
            labj[n] = 9 * region(ix * 4 + jwx[n]) + 3 * region(iy * 4 + jwy[n]) + region(iz * 4 + jwz[n]);
        }
        #pragma unroll
        for (int mm = 0; mm < 2; ++mm)
            #pragma unroll
            for (int r = 0; r < 4; ++r) {
                int i = rb + mm * 16 + kh * 4 + r;
                int iwx = i >> 4, iwy = (i >> 2) & 3, iwz = i & 3;
                int labi = 9 * region(ix * 4 + iwx) + 3 * region(iy * 4 + iwy) + region(iz * 4 + iwz);
                #pragma unroll
                for (int n = 0; n < 4; ++n) {
                    float bias = posl[((iwx - jwx[n] + 3) * 7 + (iwy - jwy[n] + 3)) * 7 + (iwz - jwz[n] + 3)];
                    sa[mm][n][r] += bias + (labi != labj[n] ? -1e9f : 0.0f);
                }
                float mx = fmaxf(fmaxf(sa[mm][0][r], sa[mm][1][r]), fmaxf(sa[mm][2][r], sa[mm][3][r]));
                #pragma unroll
                for (int s = 1; s < 16; s <<= 1) mx = fmaxf(mx, __shfl_xor(mx, s, 16));
                float e0 = __expf(sa[mm][0][r] - mx), e1 = __expf(sa[mm][1][r] - mx);
                float e2 = __expf(sa[mm][2][r] - mx), e3 = __expf(sa[mm][3][r] - mx);
                float sum = e0 + e1 + e2 + e3;
                #pragma unroll
                for (int s = 1; s < 16; s <<= 1) sum += __shfl_xor(sum, s, 16);
                float rs = 1.0f / sum;
                sa[mm][0][r] = e0 * rs; sa[mm][1][r] = e1 * rs;
                sa[mm][2][r] = e2 * rs; sa[mm][3][r] = e3 * rs;
            }
    }
    __syncthreads();   // S2: all q/k reads complete -> safe to overwrite with P

    // write P (bf16) over q/k region
    #pragma unroll
    for (int mm = 0; mm < 2; ++mm)
        #pragma unroll
        for (int n = 0; n < 4; ++n)
            #pragma unroll
            for (int r = 0; r < 4; ++r)
                P_s[(h3 * 64 + rb + mm * 16 + kh * 4 + r) * 72 + n * 16 + lr] = f2bf(sa[mm][n][r]);
    __syncthreads();   // S3: P visible (also orders the alias)

    // ---- P3: PV + write a_out ----
    {
        f32x4 oa[2][2];
        #pragma unroll
        for (int mm = 0; mm < 2; ++mm)
            #pragma unroll
            for (int n = 0; n < 2; ++n) oa[mm][n] = (f32x4){0.f, 0.f, 0.f, 0.f};
        #pragma unroll
        for (int ks = 0; ks < 2; ++ks) {
            int k0 = ks * 32;
            bf16x8 ap[2], bv[2];
            #pragma unroll
            for (int mm = 0; mm < 2; ++mm)
                ap[mm] = *(const bf16x8*)&P_s[(h3 * 64 + rb + mm * 16 + lr) * 72 + k0 + kh * 8];
            #pragma unroll
            for (int n = 0; n < 2; ++n)
                bv[n] = *(const bf16x8*)&vT[(h3 * 32 + n * 16 + lr) * 72 + k0 + kh * 8];
            #pragma unroll
            for (int mm = 0; mm < 2; ++mm)
                #pragma unroll
                for (int n = 0; n < 2; ++n)
                    oa[mm][n] = __builtin_amdgcn_mfma_f32_16x16x32_bf16(ap[mm], bv[n], oa[mm][n], 0, 0, 0);
        }
        #pragma unroll
        for (int mm = 0; mm < 2; ++mm)
            #pragma unroll
            for (int n = 0; n < 2; ++n)
                #pragma unroll
                for (int r = 0; r < 4; ++r) {
                    int tok = rb + mm * 16 + kh * 4 + r;
                    a_out[((size_t)win * 64 + tok) * 96 + h3 * 32 + n * 16 + lr] = f2bf(oa[mm][n][r]);
                }
    }
}

// ---------------- K3: proj + residual + LN2 + MLP + residual, high-occupancy ----------------
// 256 thr (4 waves) per window. Phase A barrier-free (wave owns 16 tokens; LN2 via
// 16-lane shuffles; x1 in f32 regs). MLP: 4 hidden chunks of 96, weights partitioned
// across waves. Output staged in an LDS f32 tile overlaying the ENTIRE xl+gl arena
// (both dead after the MLP) and flushed with coalesced float4 stores.
// LDS arena: 13312 shorts = 26.6 KB -> 6 blocks/CU (24 waves, 75% ceiling).
__global__ __launch_bounds__(256, 6) void proj_mlp5_kernel(
    const unsigned short* __restrict__ a_out,
    const unsigned short* __restrict__ wo_t, const float* __restrict__ b_out,
    const float* __restrict__ x,
    const float* __restrict__ g2, const float* __restrict__ bt2,
    const unsigned short* __restrict__ w1_t, const float* __restrict__ b1,
    const unsigned short* __restrict__ w2_t, const float* __restrict__ b2,
    float* __restrict__ out)
{
    __shared__ __align__(16) unsigned short SH[13312];   // xl @0, gl @6656; tile overlays all
    unsigned short* xl = SH;          // [64][104] bf16
    unsigned short* gl = SH + 6656;   // [64][104] bf16
    float* tile = (float*)SH;         // [64][100] f32 (25.6 KB <= 26.6 KB)

    int win = blockIdx.x;
    int tid = threadIdx.x;
    int w = tid >> 6, lane = tid & 63, lr = lane & 15, kh = lane >> 4;
    int ix = win >> 8, iy = (win >> 4) & 15, iz = win & 15;
    int tb = w * 16;

    // wave w owns tokens tb + kh*4 + r  (wx=w, wy=kh, wz=r)
    int px = (ix * 4 + w + 2) & 63;
    int py = (iy * 4 + kh + 2) & 63;
    int rowbase = (px * 64 + py) * 64;
    int o[4];
    #pragma unroll
    for (int r = 0; r < 4; ++r) o[r] = (rowbase + ((iz * 4 + r + 2) & 63)) * 96;

    // ---- Phase A: proj GEMM (M=16/wave) + x residual + in-register LN2 -> xl ----
    float x1v[6][4];
    {
        f32x4 pa[6];
        #pragma unroll
        for (int n = 0; n < 6; ++n) pa[n] = (f32x4){0.f, 0.f, 0.f, 0.f};
        #pragma unroll
        for (int ks = 0; ks < 3; ++ks) {
            int k0 = ks * 32;
            bf16x8 a = *(const bf16x8*)(a_out + ((size_t)win * 64 + tb + lr) * 96 + k0 + kh * 8);
            #pragma unroll
            for (int n = 0; n < 6; ++n) {
                bf16x8 bb = *(const bf16x8*)(wo_t + (size_t)(n * 16 + lr) * 96 + k0 + kh * 8);
                pa[n] = __builtin_amdgcn_mfma_f32_16x16x32_bf16(a, bb, pa[n], 0, 0, 0);
            }
        }
        #pragma unroll
        for (int n = 0; n < 6; ++n) {
            int c = n * 16 + lr;
            float bo = b_out[c];
            #pragma unroll
            for (int r = 0; r < 4; ++r)
                x1v[n][r] = x[o[r] + c] + pa[n][r] + bo;
        }
        float g2c[6], bc2[6];
        #pragma unroll
        for (int n = 0; n < 6; ++n) { g2c[n] = g2[n * 16 + lr]; bc2[n] = bt2[n * 16 + lr]; }
        #pragma unroll
        for (int r = 0; r < 4; ++r) {
            float s = 0.f, sq = 0.f;
            #pragma unroll
            for (int n = 0; n < 6; ++n) { s += x1v[n][r]; sq += x1v[n][r] * x1v[n][r]; }
            #pragma unroll
            for (int m = 8; m >= 1; m >>= 1) { s += __shfl_xor(s, m, 16); sq += __shfl_xor(sq, m, 16); }
            float mean = s * (1.0f / 96.0f);
            float var = sq * (1.0f / 96.0f) - mean * mean;
            float rstd = rsqrtf(var + 1e-5f);
            int t = tb + kh * 4 + r;
            #pragma unroll
            for (int n = 0; n < 6; ++n)
                xl[t * 104 + n * 16 + lr] = f2bf((x1v[n][r] - mean) * rstd * g2c[n] + bc2[n]);
        }
    }
    __syncthreads();

    // ---- MLP: 4 hidden chunks of 96; wave grid wm(2 M-bands of 32) x wn(2 N-bands of 48) ----
    int wm = w & 1, wn = w >> 1;
    f32x4 acc2[2][3];
    #pragma unroll
    for (int mf = 0; mf < 2; ++mf)
        #pragma unroll
        for (int nf = 0; nf < 3; ++nf) acc2[mf][nf] = (f32x4){0.f, 0.f, 0.f, 0.f};

    for (int ch = 0; ch < 4; ++ch) {
        // G1 chunk: [64 x 96]; cols = ch*96 + wn*48 + nf*16
        f32x4 a1[2][3];
        #pragma unroll
        for (int mf = 0; mf < 2; ++mf)
            #pragma unroll
            for (int nf = 0; nf < 3; ++nf) a1[mf][nf] = (f32x4){0.f, 0.f, 0.f, 0.f};
        #pragma unroll
        for (int ks = 0; ks < 3; ++ks) {
            int k0 = ks * 32;
            bf16x8 af[2], bfr[3];
            #pragma unroll
            for (int mf = 0; mf < 2; ++mf)
                af[mf] = *(const bf16x8*)&xl[(wm * 32 + mf * 16 + lr) * 104 + k0 + kh * 8];
            #pragma unroll
            for (int nf = 0; nf < 3; ++nf)
                bfr[nf] = *(const bf16x8*)(w1_t + (size_t)(ch * 96 + wn * 48 + nf * 16 + lr) * 96 + k0 + kh * 8);
            #pragma unroll
            for (int mf = 0; mf < 2; ++mf)
                #pragma unroll
                for (int nf = 0; nf < 3; ++nf)
                    a1[mf][nf] = __builtin_amdgcn_mfma_f32_16x16x32_bf16(af[mf], bfr[nf], a1[mf][nf], 0, 0, 0);
        }
        #pragma unroll
        for (int nf = 0; nf < 3; ++nf) {
            int lcol = wn * 48 + nf * 16 + lr;
            float bias = b1[ch * 96 + lcol];
            #pragma unroll
            for (int mf = 0; mf < 2; ++mf)
                #pragma unroll
                for (int r = 0; r < 4; ++r) {
                    float u = a1[mf][nf][r] + bias;
                    float t = 1.5957691216057308f * (u + 0.044715f * u * u * u);
                    float ge = u * __builtin_amdgcn_rcpf(1.0f + __expf(-t));
                    gl[(wm * 32 + mf * 16 + kh * 4 + r) * 104 + lcol] = f2bf(ge);
                }
        }
        __syncthreads();
        // G2 partial: [64 x 96]; K = this chunk's 96
        #pragma unroll
        for (int kc = 0; kc < 3; ++kc) {
            int k0 = kc * 32;
            bf16x8 ag[2];
            #pragma unroll
            for (int mf = 0; mf < 2; ++mf)
                ag[mf] = *(const bf16x8*)&gl[(wm * 32 + mf * 16 + lr) * 104 + k0 + kh * 8];
            #pragma unroll
            for (int nf = 0; nf < 3; ++nf) {
                bf16x8 bb = *(const bf16x8*)(w2_t + (size_t)(wn * 48 + nf * 16 + lr) * 384 + ch * 96 + k0 + kh * 8);
                #pragma unroll
                for (int mf = 0; mf < 2; ++mf)
                    acc2[mf][nf] = __builtin_amdgcn_mfma_f32_16x16x32_bf16(ag[mf], bb, acc2[mf][nf], 0, 0, 0);
            }
        }
        __syncthreads();   // gl reuse (next G1)
    }

    // ---- Output staging: tile = x1 (f32) overlaying the arena, += mlp + b2, coalesced flush ----
    #pragma unroll
    for (int r = 0; r < 4; ++r) {
        int t = tb + kh * 4 + r;
        #pragma unroll
        for (int n = 0; n < 6; ++n)
            tile[t * 100 + n * 16 + lr] = x1v[n][r];
    }
    __syncthreads();
    #pragma unroll
    for (int nf = 0; nf < 3; ++nf) {
        int col = wn * 48 + nf * 16 + lr;
        float bc = b2[col];
        #pragma unroll
        for (int mf = 0; mf < 2; ++mf)
            #pragma unroll
            for (int r = 0; r < 4; ++r) {
                int row = wm * 32 + mf * 16 + kh * 4 + r;
                tile[row * 100 + col] += acc2[mf][nf][r] + bc;
            }
    }
    __syncthreads();
    // flush: 1536 float4; adjacent lanes -> adjacent 16-B chunks; every 128-B line
    // of every token row (384 B = 3 lines, 128-B aligned) written by one instruction.
    #pragma unroll
    for (int j = 0; j < 6; ++j) {
        int f4 = j * 256 + tid;
        int token = f4 / 24, c4 = f4 % 24;
        int wx = token >> 4, wy = (token >> 2) & 3, wz = token & 3;
        int qx = (ix * 4 + wx + 2) & 63, qy = (iy * 4 + wy + 2) & 63, qz = (iz * 4 + wz + 2) & 63;
        size_t g = ((size_t)((qx * 64 + qy) * 64 + qz)) * 96 + c4 * 4;
        f32x4 v = *(const f32x4*)&tile[token * 100 + c4 * 4];
        *(f32x4*)&out[g] = v;
    }
}

extern "C" void kernel_launch(void* const* d_in, const int* in_sizes, int n_in,
                              void* d_out, int out_size, void* d_ws, size_t ws_size,
                              hipStream_t stream) {
    const float* x       = (const float*)d_in[0];
    const float* Wqkv    = (const float*)d_in[1];
    const float* Wout    = (const float*)d_in[2];
    const float* b_out   = (const float*)d_in[3];
    const float* pos_tab = (const float*)d_in[4];
    const float* ln1_g   = (const float*)d_in[5];
    const float* ln1_b   = (const float*)d_in[6];
    const float* ln2_g   = (const float*)d_in[7];
    const float* ln2_b   = (const float*)d_in[8];
    const float* W1      = (const float*)d_in[9];
    const float* b1      = (const float*)d_in[10];
    const float* W2      = (const float*)d_in[11];
    const float* b2      = (const float*)d_in[12];
    float* out = (float*)d_out;

    char* ws = (char*)d_ws;
    unsigned short* y     = (unsigned short*)(ws);              // 48 MB (LN1 output, window-major)
    unsigned short* a_out = (unsigned short*)(ws + 50331648);   // 48 MB (attention output)
    unsigned short* wq_t  = (unsigned short*)(ws + 100663296);  // 55296 B
    unsigned short* wo_t  = wq_t + 27648;                       // 18432 B
    unsigned short* w1_t  = wo_t + 9216;                        // 73728 B
    unsigned short* w2_t  = w1_t + 36864;                       // 73728 B

    convert_weights<<<432, 256, 0, stream>>>(Wqkv, Wout, W1, W2, wq_t, wo_t, w1_t, w2_t);
    ln1_shift_kernel<<<32768, 256, 0, stream>>>(x, ln1_g, ln1_b, y);
    qkv_attn_kernel<<<NWIN, 384, 0, stream>>>(y, wq_t, pos_tab, a_out);
    proj_mlp5_kernel<<<NWIN, 256, 0, stream>>>(a_out, wo_t, b_out, x,
                                               ln2_g, ln2_b, w1_t, b1, w2_t, b2, out);
}

// Round 9
// 264.535 us; speedup vs baseline: 1.5159x; 1.5159x over previous
//
#include <hip/hip_runtime.h>

typedef __attribute__((ext_vector_type(8))) short bf16x8;
typedef __attribute__((ext_vector_type(4))) short s16x4;
typedef __attribute__((ext_vector_type(4))) float f32x4;

#define NTOK 262144   // 64^3 tokens
#define NWIN 4096     // 16^3 windows of 4^3

__device__ __forceinline__ unsigned short f2bf(float f) {
    unsigned int u = __float_as_uint(f);
    return (unsigned short)((u + 0x7FFFu + ((u >> 16) & 1u)) >> 16);
}
__device__ __forceinline__ float bf2f(unsigned short u) {
    return __uint_as_float(((unsigned int)u) << 16);
}
__device__ __forceinline__ int region(int g) { return (g >= 60) + (g >= 62); }

// ---------------- K0: weight convert + transpose to N-major bf16 ----------------
__global__ void convert_weights(const float* __restrict__ Wqkv, const float* __restrict__ Wout,
                                const float* __restrict__ W1, const float* __restrict__ W2,
                                unsigned short* __restrict__ wq_t, unsigned short* __restrict__ wo_t,
                                unsigned short* __restrict__ w1_t, unsigned short* __restrict__ w2_t) {
    int idx = blockIdx.x * blockDim.x + threadIdx.x;
    if (idx < 27648) {                       // wq_t[288][96] = Wqkv[96][288]^T
        int n = idx / 96, k = idx % 96;
        wq_t[idx] = f2bf(Wqkv[k * 288 + n]);
    } else if (idx < 27648 + 9216) {         // wo_t[96][96]
        int i = idx - 27648; int n = i / 96, k = i % 96;
        wo_t[i] = f2bf(Wout[k * 96 + n]);
    } else if (idx < 27648 + 9216 + 36864) { // w1_t[384][96]
        int i = idx - 36864; int n = i / 96, k = i % 96;
        w1_t[i] = f2bf(W1[k * 384 + n]);
    } else if (idx < 110592) {               // w2_t[96][384]
        int i = idx - 73728; int n = i / 384, k = i % 384;
        w2_t[i] = f2bf(W2[k * 96 + n]);
    }
}

// ---------------- K1: LN1 + cyclic shift(-2) + window-major relayout ----------------
__global__ __launch_bounds__(256) void ln1_shift_kernel(const float* __restrict__ x,
                                                        const float* __restrict__ g,
                                                        const float* __restrict__ b,
                                                        unsigned short* __restrict__ y) {
    int tid = blockIdx.x * blockDim.x + threadIdx.x;
    int token = tid >> 5;          // output (shifted-frame) token
    int lane = tid & 31;
    if (token >= NTOK) return;
    int pz = token & 63, py = (token >> 6) & 63, px = token >> 12;
    int sx = (px + 2) & 63, sy = (py + 2) & 63, sz = (pz + 2) & 63;   // roll(x,-2)
    size_t src = ((size_t)((sx * 64 + sy) * 64 + sz)) * 96;
    float v0 = x[src + lane], v1 = x[src + 32 + lane], v2 = x[src + 64 + lane];
    float s = v0 + v1 + v2;
    float sq = v0 * v0 + v1 * v1 + v2 * v2;
    #pragma unroll
    for (int m = 16; m >= 1; m >>= 1) { s += __shfl_xor(s, m, 32); sq += __shfl_xor(sq, m, 32); }
    float mean = s * (1.0f / 96.0f);
    float var = sq * (1.0f / 96.0f) - mean * mean;
    float rstd = rsqrtf(var + 1e-5f);
    int win = ((px >> 2) * 16 + (py >> 2)) * 16 + (pz >> 2);
    int loc = ((px & 3) * 4 + (py & 3)) * 4 + (pz & 3);
    size_t dst = ((size_t)(win * 64 + loc)) * 96;
    y[dst + lane]      = f2bf((v0 - mean) * rstd * g[lane]      + b[lane]);
    y[dst + 32 + lane] = f2bf((v1 - mean) * rstd * g[lane + 32] + b[lane + 32]);
    y[dst + 64 + lane] = f2bf((v2 - mean) * rstd * g[lane + 64] + b[lane + 64]);
}

// ---------------- K2: FUSED QKV GEMM + attention (one window, 6 waves) ----------------
__global__ __launch_bounds__(384, 4) void qkv_attn_kernel(
    const unsigned short* __restrict__ y,
    const unsigned short* __restrict__ wq_t,
    const float* __restrict__ pos_tab,
    unsigned short* __restrict__ a_out)
{
    __shared__ __align__(16) unsigned short SH[22272];
    __shared__ __align__(16) float posl[344];
    unsigned short* q_s = SH;             // [3][64][40]
    unsigned short* k_s = SH + 7680;      // [3][64][40]
    unsigned short* vT  = SH + 15360;     // [3][32][72]
    unsigned short* P_s = SH;             // [3][64][72]  (aliases q+k after S2)

    int win = blockIdx.x;
    int tid = threadIdx.x;
    int w = tid >> 6, lane = tid & 63, lr = lane & 15, kh = lane >> 4;
    int ix = win >> 8, iy = (win >> 4) & 15, iz = win & 15;

    if (tid < 343) posl[tid] = pos_tab[tid];

    // ---- P1: QKV GEMM (A = y from global, B = wq_t); scatter to q_s/k_s/vT ----
    {
        f32x4 acc3[4][3];
        #pragma unroll
        for (int m = 0; m < 4; ++m)
            #pragma unroll
            for (int n = 0; n < 3; ++n) acc3[m][n] = (f32x4){0.f, 0.f, 0.f, 0.f};
        #pragma unroll
        for (int ks = 0; ks < 3; ++ks) {
            int k0 = ks * 32;
            bf16x8 a[4], bb[3];
            #pragma unroll
            for (int m = 0; m < 4; ++m)
                a[m] = *(const bf16x8*)(y + ((size_t)win * 64 + m * 16 + lr) * 96 + k0 + kh * 8);
            #pragma unroll
            for (int n = 0; n < 3; ++n)
                bb[n] = *(const bf16x8*)(wq_t + (size_t)(w * 48 + n * 16 + lr) * 96 + k0 + kh * 8);
            #pragma unroll
            for (int m = 0; m < 4; ++m)
                #pragma unroll
                for (int n = 0; n < 3; ++n)
                    acc3[m][n] = __builtin_amdgcn_mfma_f32_16x16x32_bf16(a[m], bb[n], acc3[m][n], 0, 0, 0);
        }
        const float scale = 0.17677669529663689f;   // 32^-0.5 folded into Q
        #pragma unroll
        for (int n = 0; n < 3; ++n) {
            int base = w * 48 + n * 16;
            int qq = base / 96, cc0 = base % 96;
            int hh = cc0 >> 5, d0 = cc0 & 31;
            if (qq == 2) {
                #pragma unroll
                for (int m = 0; m < 4; ++m) {
                    s16x4 pv;
                    #pragma unroll
                    for (int r = 0; r < 4; ++r) pv[r] = (short)f2bf(acc3[m][n][r]);
                    *(s16x4*)&vT[(hh * 32 + d0 + lr) * 72 + m * 16 + kh * 4] = pv;
                }
            } else {
                unsigned short* dst = (qq == 0) ? q_s : k_s;
                float sc = (qq == 0) ? scale : 1.0f;
                #pragma unroll
                for (int m = 0; m < 4; ++m)
                    #pragma unroll
                    for (int r = 0; r < 4; ++r) {
                        int tok = m * 16 + kh * 4 + r;
                        dst[(hh * 64 + tok) * 40 + d0 + lr] = f2bf(acc3[m][n][r] * sc);
                    }
            }
        }
    }
    __syncthreads();   // S1: q/k/vT + posl visible

    // ---- P2: QK^T + bias + mask + softmax (2 waves per head) ----
    int h3 = w >> 1, rb = (w & 1) * 32;
    f32x4 sa[2][4];
    {
        bf16x8 aq[2], bk[4];
        #pragma unroll
        for (int mm = 0; mm < 2; ++mm)
            aq[mm] = *(const bf16x8*)&q_s[(h3 * 64 + rb + mm * 16 + lr) * 40 + kh * 8];
        #pragma unroll
        for (int n = 0; n < 4; ++n)
            bk[n] = *(const bf16x8*)&k_s[(h3 * 64 + n * 16 + lr) * 40 + kh * 8];
        #pragma unroll
        for (int mm = 0; mm < 2; ++mm)
            #pragma unroll
            for (int n = 0; n < 4; ++n)
                sa[mm][n] = __builtin_amdgcn_mfma_f32_16x16x32_bf16(aq[mm], bk[n], (f32x4){0.f,0.f,0.f,0.f}, 0, 0, 0);

        int labj[4], jwx[4], jwy[4], jwz[4];
        #pragma unroll
        for (int n = 0; n < 4; ++n) {
            int j = n * 16 + lr;
            jwx[n] = j >> 4; jwy[n] = (j >> 2) & 3; jwz[n] = j & 3;
            labj[n] = 9 * region(ix * 4 + jwx[n]) + 3 * region(iy * 4 + jwy[n]) + region(iz * 4 + jwz[n]);
        }
        #pragma unroll
        for (int mm = 0; mm < 2; ++mm)
            #pragma unroll
            for (int r = 0; r < 4; ++r) {
                int i = rb + mm * 16 + kh * 4 + r;
                int iwx = i >> 4, iwy = (i >> 2) & 3, iwz = i & 3;
                int labi = 9 * region(ix * 4 + iwx) + 3 * region(iy * 4 + iwy) + region(iz * 4 + iwz);
                #pragma unroll
                for (int n = 0; n < 4; ++n) {
                    float bias = posl[((iwx - jwx[n] + 3) * 7 + (iwy - jwy[n] + 3)) * 7 + (iwz - jwz[n] + 3)];
                    sa[mm][n][r] += bias + (labi != labj[n] ? -1e9f : 0.0f);
                }
                float mx = fmaxf(fmaxf(sa[mm][0][r], sa[mm][1][r]), fmaxf(sa[mm][2][r], sa[mm][3][r]));
                #pragma unroll
                for (int s = 1; s < 16; s <<= 1) mx = fmaxf(mx, __shfl_xor(mx, s, 16));
                float e0 = __expf(sa[mm][0][r] - mx), e1 = __expf(sa[mm][1][r] - mx);
                float e2 = __expf(sa[mm][2][r] - mx), e3 = __expf(sa[mm][3][r] - mx);
                float sum = e0 + e1 + e2 + e3;
                #pragma unroll
                for (int s = 1; s < 16; s <<= 1) sum += __shfl_xor(sum, s, 16);
                float rs = 1.0f / sum;
                sa[mm][0][r] = e0 * rs; sa[mm][1][r] = e1 * rs;
                sa[mm][2][r] = e2 * rs; sa[mm][3][r] = e3 * rs;
            }
    }
    __syncthreads();   // S2: all q/k reads complete -> safe to overwrite with P

    // write P (bf16) over q/k region
    #pragma unroll
    for (int mm = 0; mm < 2; ++mm)
        #pragma unroll
        for (int n = 0; n < 4; ++n)
            #pragma unroll
            for (int r = 0; r < 4; ++r)
                P_s[(h3 * 64 + rb + mm * 16 + kh * 4 + r) * 72 + n * 16 + lr] = f2bf(sa[mm][n][r]);
    __syncthreads();   // S3: P visible (also orders the alias)

    // ---- P3: PV + write a_out ----
    {
        f32x4 oa[2][2];
        #pragma unroll
        for (int mm = 0; mm < 2; ++mm)
            #pragma unroll
            for (int n = 0; n < 2; ++n) oa[mm][n] = (f32x4){0.f, 0.f, 0.f, 0.f};
        #pragma unroll
        for (int ks = 0; ks < 2; ++ks) {
            int k0 = ks * 32;
            bf16x8 ap[2], bv[2];
            #pragma unroll
            for (int mm = 0; mm < 2; ++mm)
                ap[mm] = *(const bf16x8*)&P_s[(h3 * 64 + rb + mm * 16 + lr) * 72 + k0 + kh * 8];
            #pragma unroll
            for (int n = 0; n < 2; ++n)
                bv[n] = *(const bf16x8*)&vT[(h3 * 32 + n * 16 + lr) * 72 + k0 + kh * 8];
            #pragma unroll
            for (int mm = 0; mm < 2; ++mm)
                #pragma unroll
                for (int n = 0; n < 2; ++n)
                    oa[mm][n] = __builtin_amdgcn_mfma_f32_16x16x32_bf16(ap[mm], bv[n], oa[mm][n], 0, 0, 0);
        }
        #pragma unroll
        for (int mm = 0; mm < 2; ++mm)
            #pragma unroll
            for (int n = 0; n < 2; ++n)
                #pragma unroll
                for (int r = 0; r < 4; ++r) {
                    int tok = rb + mm * 16 + kh * 4 + r;
                    a_out[((size_t)win * 64 + tok) * 96 + h3 * 32 + n * 16 + lr] = f2bf(oa[mm][n][r]);
                }
    }
}

// ---------------- K3: proj + residual + LN2 + MLP + residual, high-occupancy ----------------
// 256 thr (4 waves) per window. Same as round 8 but __launch_bounds__(256,4):
// round 8's (256,6) capped VGPR at 85 and the allocator spilled to scratch
// (VGPR_Count 40, FETCH 82->271 MB, WRITE 115->435 MB). With cap 128 the kernel
// lands at ~64-80 VGPR, zero spill; LDS 26.6 KB still allows up to 6 blocks/CU.
__global__ __launch_bounds__(256, 4) void proj_mlp5_kernel(
    const unsigned short* __restrict__ a_out,
    const unsigned short* __restrict__ wo_t, const float* __restrict__ b_out,
    const float* __restrict__ x,
    const float* __restrict__ g2, const float* __restrict__ bt2,
    const unsigned short* __restrict__ w1_t, const float* __restrict__ b1,
    const unsigned short* __restrict__ w2_t, const float* __restrict__ b2,
    float* __restrict__ out)
{
    __shared__ __align__(16) unsigned short SH[13312];   // xl @0, gl @6656; tile overlays all
    unsigned short* xl = SH;          // [64][104] bf16
    unsigned short* gl = SH + 6656;   // [64][104] bf16
    float* tile = (float*)SH;         // [64][100] f32 (25.6 KB <= 26.6 KB)

    int win = blockIdx.x;
    int tid = threadIdx.x;
    int w = tid >> 6, lane = tid & 63, lr = lane & 15, kh = lane >> 4;
    int ix = win >> 8, iy = (win >> 4) & 15, iz = win & 15;
    int tb = w * 16;

    // wave w owns tokens tb + kh*4 + r  (wx=w, wy=kh, wz=r)
    int px = (ix * 4 + w + 2) & 63;
    int py = (iy * 4 + kh + 2) & 63;
    int rowbase = (px * 64 + py) * 64;
    int o[4];
    #pragma unroll
    for (int r = 0; r < 4; ++r) o[r] = (rowbase + ((iz * 4 + r + 2) & 63)) * 96;

    // ---- Phase A: proj GEMM (M=16/wave) + x residual + in-register LN2 -> xl ----
    float x1v[6][4];
    {
        f32x4 pa[6];
        #pragma unroll
        for (int n = 0; n < 6; ++n) pa[n] = (f32x4){0.f, 0.f, 0.f, 0.f};
        #pragma unroll
        for (int ks = 0; ks < 3; ++ks) {
            int k0 = ks * 32;
            bf16x8 a = *(const bf16x8*)(a_out + ((size_t)win * 64 + tb + lr) * 96 + k0 + kh * 8);
            #pragma unroll
            for (int n = 0; n < 6; ++n) {
                bf16x8 bb = *(const bf16x8*)(wo_t + (size_t)(n * 16 + lr) * 96 + k0 + kh * 8);
                pa[n] = __builtin_amdgcn_mfma_f32_16x16x32_bf16(a, bb, pa[n], 0, 0, 0);
            }
        }
        #pragma unroll
        for (int n = 0; n < 6; ++n) {
            int c = n * 16 + lr;
            float bo = b_out[c];
            #pragma unroll
            for (int r = 0; r < 4; ++r)
                x1v[n][r] = x[o[r] + c] + pa[n][r] + bo;
        }
        float g2c[6], bc2[6];
        #pragma unroll
        for (int n = 0; n < 6; ++n) { g2c[n] = g2[n * 16 + lr]; bc2[n] = bt2[n * 16 + lr]; }
        #pragma unroll
        for (int r = 0; r < 4; ++r) {
            float s = 0.f, sq = 0.f;
            #pragma unroll
            for (int n = 0; n < 6; ++n) { s += x1v[n][r]; sq += x1v[n][r] * x1v[n][r]; }
            #pragma unroll
            for (int m = 8; m >= 1; m >>= 1) { s += __shfl_xor(s, m, 16); sq += __shfl_xor(sq, m, 16); }
            float mean = s * (1.0f / 96.0f);
            float var = sq * (1.0f / 96.0f) - mean * mean;
            float rstd = rsqrtf(var + 1e-5f);
            int t = tb + kh * 4 + r;
            #pragma unroll
            for (int n = 0; n < 6; ++n)
                xl[t * 104 + n * 16 + lr] = f2bf((x1v[n][r] - mean) * rstd * g2c[n] + bc2[n]);
        }
    }
    __syncthreads();

    // ---- MLP: 4 hidden chunks of 96; wave grid wm(2 M-bands of 32) x wn(2 N-bands of 48) ----
    int wm = w & 1, wn = w >> 1;
    f32x4 acc2[2][3];
    #pragma unroll
    for (int mf = 0; mf < 2; ++mf)
        #pragma unroll
        for (int nf = 0; nf < 3; ++nf) acc2[mf][nf] = (f32x4){0.f, 0.f, 0.f, 0.f};

    for (int ch = 0; ch < 4; ++ch) {
        // G1 chunk: [64 x 96]; cols = ch*96 + wn*48 + nf*16
        f32x4 a1[2][3];
        #pragma unroll
        for (int mf = 0; mf < 2; ++mf)
            #pragma unroll
            for (int nf = 0; nf < 3; ++nf) a1[mf][nf] = (f32x4){0.f, 0.f, 0.f, 0.f};
        #pragma unroll
        for (int ks = 0; ks < 3; ++ks) {
            int k0 = ks * 32;
            bf16x8 af[2], bfr[3];
            #pragma unroll
            for (int mf = 0; mf < 2; ++mf)
                af[mf] = *(const bf16x8*)&xl[(wm * 32 + mf * 16 + lr) * 104 + k0 + kh * 8];
            #pragma unroll
            for (int nf = 0; nf < 3; ++nf)
                bfr[nf] = *(const bf16x8*)(w1_t + (size_t)(ch * 96 + wn * 48 + nf * 16 + lr) * 96 + k0 + kh * 8);
            #pragma unroll
            for (int mf = 0; mf < 2; ++mf)
                #pragma unroll
                for (int nf = 0; nf < 3; ++nf)
                    a1[mf][nf] = __builtin_amdgcn_mfma_f32_16x16x32_bf16(af[mf], bfr[nf], a1[mf][nf], 0, 0, 0);
        }
        #pragma unroll
        for (int nf = 0; nf < 3; ++nf) {
            int lcol = wn * 48 + nf * 16 + lr;
            float bias = b1[ch * 96 + lcol];
            #pragma unroll
            for (int mf = 0; mf < 2; ++mf)
                #pragma unroll
                for (int r = 0; r < 4; ++r) {
                    float u = a1[mf][nf][r] + bias;
                    float t = 1.5957691216057308f * (u + 0.044715f * u * u * u);
                    float ge = u * __builtin_amdgcn_rcpf(1.0f + __expf(-t));
                    gl[(wm * 32 + mf * 16 + kh * 4 + r) * 104 + lcol] = f2bf(ge);
                }
        }
        __syncthreads();
        // G2 partial: [64 x 96]; K = this chunk's 96
        #pragma unroll
        for (int kc = 0; kc < 3; ++kc) {
            int k0 = kc * 32;
            bf16x8 ag[2];
            #pragma unroll
            for (int mf = 0; mf < 2; ++mf)
                ag[mf] = *(const bf16x8*)&gl[(wm * 32 + mf * 16 + lr) * 104 + k0 + kh * 8];
            #pragma unroll
            for (int nf = 0; nf < 3; ++nf) {
                bf16x8 bb = *(const bf16x8*)(w2_t + (size_t)(wn * 48 + nf * 16 + lr) * 384 + ch * 96 + k0 + kh * 8);
                #pragma unroll
                for (int mf = 0; mf < 2; ++mf)
                    acc2[mf][nf] = __builtin_amdgcn_mfma_f32_16x16x32_bf16(ag[mf], bb, acc2[mf][nf], 0, 0, 0);
            }
        }
        __syncthreads();   // gl reuse (next G1)
    }

    // ---- Output staging: tile = x1 (f32) overlaying the arena, += mlp + b2, coalesced flush ----
    #pragma unroll
    for (int r = 0; r < 4; ++r) {
        int t = tb + kh * 4 + r;
        #pragma unroll
        for (int n = 0; n < 6; ++n)
            tile[t * 100 + n * 16 + lr] = x1v[n][r];
    }
    __syncthreads();
    #pragma unroll
    for (int nf = 0; nf < 3; ++nf) {
        int col = wn * 48 + nf * 16 + lr;
        float bc = b2[col];
        #pragma unroll
        for (int mf = 0; mf < 2; ++mf)
            #pragma unroll
            for (int r = 0; r < 4; ++r) {
                int row = wm * 32 + mf * 16 + kh * 4 + r;
                tile[row * 100 + col] += acc2[mf][nf][r] + bc;
            }
    }
    __syncthreads();
    // flush: 1536 float4; adjacent lanes -> adjacent 16-B chunks; every 128-B line
    // of every token row (384 B = 3 lines, 128-B aligned) written by one instruction.
    #pragma unroll
    for (int j = 0; j < 6; ++j) {
        int f4 = j * 256 + tid;
        int token = f4 / 24, c4 = f4 % 24;
        int wx = token >> 4, wy = (token >> 2) & 3, wz = token & 3;
        int qx = (ix * 4 + wx + 2) & 63, qy = (iy * 4 + wy + 2) & 63, qz = (iz * 4 + wz + 2) & 63;
        size_t g = ((size_t)((qx * 64 + qy) * 64 + qz)) * 96 + c4 * 4;
        f32x4 v = *(const f32x4*)&tile[token * 100 + c4 * 4];
        *(f32x4*)&out[g] = v;
    }
}

extern "C" void kernel_launch(void* const* d_in, const int* in_sizes, int n_in,
                              void* d_out, int out_size, void* d_ws, size_t ws_size,
                              hipStream_t stream) {
    const float* x       = (const float*)d_in[0];
    const float* Wqkv    = (const float*)d_in[1];
    const float* Wout    = (const float*)d_in[2];
    const float* b_out   = (const float*)d_in[3];
    const float* pos_tab = (const float*)d_in[4];
    const float* ln1_g   = (const float*)d_in[5];
    const float* ln1_b   = (const float*)d_in[6];
    const float* ln2_g   = (const float*)d_in[7];
    const float* ln2_b   = (const float*)d_in[8];
    const float* W1      = (const float*)d_in[9];
    const float* b1      = (const float*)d_in[10];
    const float* W2      = (const float*)d_in[11];
    const float* b2      = (const float*)d_in[12];
    float* out = (float*)d_out;

    char* ws = (char*)d_ws;
    unsigned short* y     = (unsigned short*)(ws);              // 48 MB (LN1 output, window-major)
    unsigned short* a_out = (unsigned short*)(ws + 50331648);   // 48 MB (attention output)
    unsigned short* wq_t  = (unsigned short*)(ws + 100663296);  // 55296 B
    unsigned short* wo_t  = wq_t + 27648;                       // 18432 B
    unsigned short* w1_t  = wo_t + 9216;                        // 73728 B
    unsigned short* w2_t  = w1_t + 36864;                       // 73728 B

    convert_weights<<<432, 256, 0, stream>>>(Wqkv, Wout, W1, W2, wq_t, wo_t, w1_t, w2_t);
    ln1_shift_kernel<<<32768, 256, 0, stream>>>(x, ln1_g, ln1_b, y);
    qkv_attn_kernel<<<NWIN, 384, 0, stream>>>(y, wq_t, pos_tab, a_out);
    proj_mlp5_kernel<<<NWIN, 256, 0, stream>>>(a_out, wo_t, b_out, x,
                                               ln2_g, ln2_b, w1_t, b1, w2_t, b2, out);
}

// Round 10
// 233.440 us; speedup vs baseline: 1.7178x; 1.1332x over previous
//
#include <hip/hip_runtime.h>

typedef __attribute__((ext_vector_type(8))) short bf16x8;
typedef __attribute__((ext_vector_type(4))) short s16x4;
typedef __attribute__((ext_vector_type(4))) float f32x4;

#define NWIN 4096     // 16^3 windows of 4^3

__device__ __forceinline__ unsigned short f2bf(float f) {
    unsigned int u = __float_as_uint(f);
    return (unsigned short)((u + 0x7FFFu + ((u >> 16) & 1u)) >> 16);
}
__device__ __forceinline__ float bf2f(unsigned short u) {
    return __uint_as_float(((unsigned int)u) << 16);
}
__device__ __forceinline__ int region(int g) { return (g >= 60) + (g >= 62); }

// ---------------- K0: weight convert + transpose to N-major bf16 ----------------
__global__ void convert_weights(const float* __restrict__ Wqkv, const float* __restrict__ Wout,
                                const float* __restrict__ W1, const float* __restrict__ W2,
                                unsigned short* __restrict__ wq_t, unsigned short* __restrict__ wo_t,
                                unsigned short* __restrict__ w1_t, unsigned short* __restrict__ w2_t) {
    int idx = blockIdx.x * blockDim.x + threadIdx.x;
    if (idx < 27648) {                       // wq_t[288][96] = Wqkv[96][288]^T
        int n = idx / 96, k = idx % 96;
        wq_t[idx] = f2bf(Wqkv[k * 288 + n]);
    } else if (idx < 27648 + 9216) {         // wo_t[96][96]
        int i = idx - 27648; int n = i / 96, k = i % 96;
        wo_t[i] = f2bf(Wout[k * 96 + n]);
    } else if (idx < 27648 + 9216 + 36864) { // w1_t[384][96]
        int i = idx - 36864; int n = i / 96, k = i % 96;
        w1_t[i] = f2bf(W1[k * 384 + n]);
    } else if (idx < 110592) {               // w2_t[96][384]
        int i = idx - 73728; int n = i / 384, k = i % 384;
        w2_t[i] = f2bf(W2[k * 96 + n]);
    }
}

// ---------------- K1: FUSED LN1 + QKV GEMM + attention (one window, 6 waves) ----------------
// LDS: q[3][64][40] (7680 sh) + k[3][64][40] (7680 sh) + vT[3][32][72] (6912 sh) = 22272 sh.
// y_s [64][104] (6656 sh) ALIASES the vT region (y dead after GEMM reads; vT written after
// the post-GEMM barrier). P[3][64][72] aliases q+k after S2. LDS 44.5KB -> 3 blocks/CU.
__global__ __launch_bounds__(384, 4) void ln_qkv_attn_kernel(
    const float* __restrict__ x,
    const float* __restrict__ ln1_g, const float* __restrict__ ln1_b,
    const unsigned short* __restrict__ wq_t,
    const float* __restrict__ pos_tab,
    unsigned short* __restrict__ a_out)
{
    __shared__ __align__(16) unsigned short SH[22272];
    __shared__ __align__(16) float posl[344];
    unsigned short* q_s = SH;             // [3][64][40]
    unsigned short* k_s = SH + 7680;      // [3][64][40]
    unsigned short* vT  = SH + 15360;     // [3][32][72]
    unsigned short* y_s = SH + 15360;     // [64][104]  (aliases vT; dead before vT written)
    unsigned short* P_s = SH;             // [3][64][72] (aliases q+k after S2)

    int win = blockIdx.x;
    int tid = threadIdx.x;
    int w = tid >> 6, lane = tid & 63, lr = lane & 15, kh = lane >> 4;
    int ix = win >> 8, iy = (win >> 4) & 15, iz = win & 15;

    if (tid < 343) posl[tid] = pos_tab[tid];

    // ---- P0: LN1 on shifted-gathered window tokens -> y_s (bf16) ----
    {
        int grp = tid >> 4, gi = tid & 15;   // 24 groups of 16 lanes
        float gv[6], bv[6];
        #pragma unroll
        for (int j = 0; j < 6; ++j) { gv[j] = ln1_g[gi + 16 * j]; bv[j] = ln1_b[gi + 16 * j]; }
        #pragma unroll
        for (int p = 0; p < 3; ++p) {
            int t = grp + p * 24;
            if (t < 64) {
                int wx = t >> 4, wy = (t >> 2) & 3, wz = t & 3;
                int sx = (ix * 4 + wx + 2) & 63, sy = (iy * 4 + wy + 2) & 63, sz = (iz * 4 + wz + 2) & 63;
                const float* src = x + ((size_t)((sx * 64 + sy) * 64 + sz)) * 96;
                float v[6]; float s = 0.f, sq = 0.f;
                #pragma unroll
                for (int j = 0; j < 6; ++j) { v[j] = src[gi + 16 * j]; s += v[j]; sq += v[j] * v[j]; }
                #pragma unroll
                for (int m = 8; m >= 1; m >>= 1) { s += __shfl_xor(s, m, 16); sq += __shfl_xor(sq, m, 16); }
                float mean = s * (1.0f / 96.0f);
                float var = sq * (1.0f / 96.0f) - mean * mean;
                float rstd = rsqrtf(var + 1e-5f);
                #pragma unroll
                for (int j = 0; j < 6; ++j)
                    y_s[t * 104 + gi + 16 * j] = f2bf((v[j] - mean) * rstd * gv[j] + bv[j]);
            }
        }
    }
    __syncthreads();   // y_s visible

    // ---- P1: QKV GEMM (A = y_s from LDS, B = wq_t from L2) ----
    f32x4 acc3[4][3];
    {
        #pragma unroll
        for (int m = 0; m < 4; ++m)
            #pragma unroll
            for (int n = 0; n < 3; ++n) acc3[m][n] = (f32x4){0.f, 0.f, 0.f, 0.f};
        #pragma unroll
        for (int ks = 0; ks < 3; ++ks) {
            int k0 = ks * 32;
            bf16x8 a[4], bb[3];
            #pragma unroll
            for (int m = 0; m < 4; ++m)
                a[m] = *(const bf16x8*)&y_s[(m * 16 + lr) * 104 + k0 + kh * 8];
            #pragma unroll
            for (int n = 0; n < 3; ++n)
                bb[n] = *(const bf16x8*)(wq_t + (size_t)(w * 48 + n * 16 + lr) * 96 + k0 + kh * 8);
            #pragma unroll
            for (int m = 0; m < 4; ++m)
                #pragma unroll
                for (int n = 0; n < 3; ++n)
                    acc3[m][n] = __builtin_amdgcn_mfma_f32_16x16x32_bf16(a[m], bb[n], acc3[m][n], 0, 0, 0);
        }
    }
    __syncthreads();   // all y_s reads complete -> safe to overwrite vT region

    // ---- scatter to q_s (pre-scaled) / k_s / vT ----
    {
        const float scale = 0.17677669529663689f;   // 32^-0.5 folded into Q
        #pragma unroll
        for (int n = 0; n < 3; ++n) {
            int base = w * 48 + n * 16;
            int qq = base / 96, cc0 = base % 96;
            int hh = cc0 >> 5, d0 = cc0 & 31;
            if (qq == 2) {
                #pragma unroll
                for (int m = 0; m < 4; ++m) {
                    s16x4 pv;
                    #pragma unroll
                    for (int r = 0; r < 4; ++r) pv[r] = (short)f2bf(acc3[m][n][r]);
                    *(s16x4*)&vT[(hh * 32 + d0 + lr) * 72 + m * 16 + kh * 4] = pv;
                }
            } else {
                unsigned short* dst = (qq == 0) ? q_s : k_s;
                float sc = (qq == 0) ? scale : 1.0f;
                #pragma unroll
                for (int m = 0; m < 4; ++m)
                    #pragma unroll
                    for (int r = 0; r < 4; ++r) {
                        int tok = m * 16 + kh * 4 + r;
                        dst[(hh * 64 + tok) * 40 + d0 + lr] = f2bf(acc3[m][n][r] * sc);
                    }
            }
        }
    }
    __syncthreads();   // S1: q/k/vT + posl visible

    // ---- P2: QK^T + bias + mask + softmax (2 waves per head) ----
    int h3 = w >> 1, rb = (w & 1) * 32;
    f32x4 sa[2][4];
    {
        bf16x8 aq[2], bk[4];
        #pragma unroll
        for (int mm = 0; mm < 2; ++mm)
            aq[mm] = *(const bf16x8*)&q_s[(h3 * 64 + rb + mm * 16 + lr) * 40 + kh * 8];
        #pragma unroll
        for (int n = 0; n < 4; ++n)
            bk[n] = *(const bf16x8*)&k_s[(h3 * 64 + n * 16 + lr) * 40 + kh * 8];
        #pragma unroll
        for (int mm = 0; mm < 2; ++mm)
            #pragma unroll
            for (int n = 0; n < 4; ++n)
                sa[mm][n] = __builtin_amdgcn_mfma_f32_16x16x32_bf16(aq[mm], bk[n], (f32x4){0.f,0.f,0.f,0.f}, 0, 0, 0);

        int labj[4], jwx[4], jwy[4], jwz[4];
        #pragma unroll
        for (int n = 0; n < 4; ++n) {
            int j = n * 16 + lr;
            jwx[n] = j >> 4; jwy[n] = (j >> 2) & 3; jwz[n] = j & 3;
            labj[n] = 9 * region(ix * 4 + jwx[n]) + 3 * region(iy * 4 + jwy[n]) + region(iz * 4 + jwz[n]);
        }
        #pragma unroll
        for (int mm = 0; mm < 2; ++mm)
            #pragma unroll
            for (int r = 0; r < 4; ++r) {
                int i = rb + mm * 16 + kh * 4 + r;
                int iwx = i >> 4, iwy = (i >> 2) & 3, iwz = i & 3;
                int labi = 9 * region(ix * 4 + iwx) + 3 * region(iy * 4 + iwy) + region(iz * 4 + iwz);
                #pragma unroll
                for (int n = 0; n < 4; ++n) {
                    float bias = posl[((iwx - jwx[n] + 3) * 7 + (iwy - jwy[n] + 3)) * 7 + (iwz - jwz[n] + 3)];
                    sa[mm][n][r] += bias + (labi != labj[n] ? -1e9f : 0.0f);
                }
                float mx = fmaxf(fmaxf(sa[mm][0][r], sa[mm][1][r]), fmaxf(sa[mm][2][r], sa[mm][3][r]));
                #pragma unroll
                for (int s = 1; s < 16; s <<= 1) mx = fmaxf(mx, __shfl_xor(mx, s, 16));
                float e0 = __expf(sa[mm][0][r] - mx), e1 = __expf(sa[mm][1][r] - mx);
                float e2 = __expf(sa[mm][2][r] - mx), e3 = __expf(sa[mm][3][r] - mx);
                float sum = e0 + e1 + e2 + e3;
                #pragma unroll
                for (int s = 1; s < 16; s <<= 1) sum += __shfl_xor(sum, s, 16);
                float rs = 1.0f / sum;
                sa[mm][0][r] = e0 * rs; sa[mm][1][r] = e1 * rs;
                sa[mm][2][r] = e2 * rs; sa[mm][3][r] = e3 * rs;
            }
    }
    __syncthreads();   // S2: all q/k reads complete -> safe to overwrite with P

    // write P (bf16) over q/k region
    #pragma unroll
    for (int mm = 0; mm < 2; ++mm)
        #pragma unroll
        for (int n = 0; n < 4; ++n)
            #pragma unroll
            for (int r = 0; r < 4; ++r)
                P_s[(h3 * 64 + rb + mm * 16 + kh * 4 + r) * 72 + n * 16 + lr] = f2bf(sa[mm][n][r]);
    __syncthreads();   // S3: P visible

    // ---- P3: PV + write a_out ----
    {
        f32x4 oa[2][2];
        #pragma unroll
        for (int mm = 0; mm < 2; ++mm)
            #pragma unroll
            for (int n = 0; n < 2; ++n) oa[mm][n] = (f32x4){0.f, 0.f, 0.f, 0.f};
        #pragma unroll
        for (int ks = 0; ks < 2; ++ks) {
            int k0 = ks * 32;
            bf16x8 ap[2], bv[2];
            #pragma unroll
            for (int mm = 0; mm < 2; ++mm)
                ap[mm] = *(const bf16x8*)&P_s[(h3 * 64 + rb + mm * 16 + lr) * 72 + k0 + kh * 8];
            #pragma unroll
            for (int n = 0; n < 2; ++n)
                bv[n] = *(const bf16x8*)&vT[(h3 * 32 + n * 16 + lr) * 72 + k0 + kh * 8];
            #pragma unroll
            for (int mm = 0; mm < 2; ++mm)
                #pragma unroll
                for (int n = 0; n < 2; ++n)
                    oa[mm][n] = __builtin_amdgcn_mfma_f32_16x16x32_bf16(ap[mm], bv[n], oa[mm][n], 0, 0, 0);
        }
        #pragma unroll
        for (int mm = 0; mm < 2; ++mm)
            #pragma unroll
            for (int n = 0; n < 2; ++n)
                #pragma unroll
                for (int r = 0; r < 4; ++r) {
                    int tok = rb + mm * 16 + kh * 4 + r;
                    a_out[((size_t)win * 64 + tok) * 96 + h3 * 32 + n * 16 + lr] = f2bf(oa[mm][n][r]);
                }
    }
}

// ---------------- K2: proj + residual + LN2 + MLP + residual (unchanged from round 9) ----------------
__global__ __launch_bounds__(256, 4) void proj_mlp5_kernel(
    const unsigned short* __restrict__ a_out,
    const unsigned short* __restrict__ wo_t, const float* __restrict__ b_out,
    const float* __restrict__ x,
    const float* __restrict__ g2, const float* __restrict__ bt2,
    const unsigned short* __restrict__ w1_t, const float* __restrict__ b1,
    const unsigned short* __restrict__ w2_t, const float* __restrict__ b2,
    float* __restrict__ out)
{
    __shared__ __align__(16) unsigned short SH[13312];   // xl @0, gl @6656; tile overlays all
    unsigned short* xl = SH;          // [64][104] bf16
    unsigned short* gl = SH + 6656;   // [64][104] bf16
    float* tile = (float*)SH;         // [64][100] f32 (25.6 KB <= 26.6 KB)

    int win = blockIdx.x;
    int tid = threadIdx.x;
    int w = tid >> 6, lane = tid & 63, lr = lane & 15, kh = lane >> 4;
    int ix = win >> 8, iy = (win >> 4) & 15, iz = win & 15;
    int tb = w * 16;

    int px = (ix * 4 + w + 2) & 63;
    int py = (iy * 4 + kh + 2) & 63;
    int rowbase = (px * 64 + py) * 64;
    int o[4];
    #pragma unroll
    for (int r = 0; r < 4; ++r) o[r] = (rowbase + ((iz * 4 + r + 2) & 63)) * 96;

    // ---- Phase A: proj GEMM (M=16/wave) + x residual + in-register LN2 -> xl ----
    float x1v[6][4];
    {
        f32x4 pa[6];
        #pragma unroll
        for (int n = 0; n < 6; ++n) pa[n] = (f32x4){0.f, 0.f, 0.f, 0.f};
        #pragma unroll
        for (int ks = 0; ks < 3; ++ks) {
            int k0 = ks * 32;
            bf16x8 a = *(const bf16x8*)(a_out + ((size_t)win * 64 + tb + lr) * 96 + k0 + kh * 8);
            #pragma unroll
            for (int n = 0; n < 6; ++n) {
                bf16x8 bb = *(const bf16x8*)(wo_t + (size_t)(n * 16 + lr) * 96 + k0 + kh * 8);
                pa[n] = __builtin_amdgcn_mfma_f32_16x16x32_bf16(a, bb, pa[n], 0, 0, 0);
            }
        }
        #pragma unroll
        for (int n = 0; n < 6; ++n) {
            int c = n * 16 + lr;
            float bo = b_out[c];
            #pragma unroll
            for (int r = 0; r < 4; ++r)
                x1v[n][r] = x[o[r] + c] + pa[n][r] + bo;
        }
        float g2c[6], bc2[6];
        #pragma unroll
        for (int n = 0; n < 6; ++n) { g2c[n] = g2[n * 16 + lr]; bc2[n] = bt2[n * 16 + lr]; }
        #pragma unroll
        for (int r = 0; r < 4; ++r) {
            float s = 0.f, sq = 0.f;
            #pragma unroll
            for (int n = 0; n < 6; ++n) { s += x1v[n][r]; sq += x1v[n][r] * x1v[n][r]; }
            #pragma unroll
            for (int m = 8; m >= 1; m >>= 1) { s += __shfl_xor(s, m, 16); sq += __shfl_xor(sq, m, 16); }
            float mean = s * (1.0f / 96.0f);
            float var = sq * (1.0f / 96.0f) - mean * mean;
            float rstd = rsqrtf(var + 1e-5f);
            int t = tb + kh * 4 + r;
            #pragma unroll
            for (int n = 0; n < 6; ++n)
                xl[t * 104 + n * 16 + lr] = f2bf((x1v[n][r] - mean) * rstd * g2c[n] + bc2[n]);
        }
    }
    __syncthreads();

    // ---- MLP: 4 hidden chunks of 96; wave grid wm(2 M-bands) x wn(2 N-bands of 48) ----
    int wm = w & 1, wn = w >> 1;
    f32x4 acc2[2][3];
    #pragma unroll
    for (int mf = 0; mf < 2; ++mf)
        #pragma unroll
        for (int nf = 0; nf < 3; ++nf) acc2[mf][nf] = (f32x4){0.f, 0.f, 0.f, 0.f};

    for (int ch = 0; ch < 4; ++ch) {
        f32x4 a1[2][3];
        #pragma unroll
        for (int mf = 0; mf < 2; ++mf)
            #pragma unroll
            for (int nf = 0; nf < 3; ++nf) a1[mf][nf] = (f32x4){0.f, 0.f, 0.f, 0.f};
        #pragma unroll
        for (int ks = 0; ks < 3; ++ks) {
            int k0 = ks * 32;
            bf16x8 af[2], bfr[3];
            #pragma unroll
            for (int mf = 0; mf < 2; ++mf)
                af[mf] = *(const bf16x8*)&xl[(wm * 32 + mf * 16 + lr) * 104 + k0 + kh * 8];
            #pragma unroll
            for (int nf = 0; nf < 3; ++nf)
                bfr[nf] = *(const bf16x8*)(w1_t + (size_t)(ch * 96 + wn * 48 + nf * 16 + lr) * 96 + k0 + kh * 8);
            #pragma unroll
            for (int mf = 0; mf < 2; ++mf)
                #pragma unroll
                for (int nf = 0; nf < 3; ++nf)
                    a1[mf][nf] = __builtin_amdgcn_mfma_f32_16x16x32_bf16(af[mf], bfr[nf], a1[mf][nf], 0, 0, 0);
        }
        #pragma unroll
        for (int nf = 0; nf < 3; ++nf) {
            int lcol = wn * 48 + nf * 16 + lr;
            float bias = b1[ch * 96 + lcol];
            #pragma unroll
            for (int mf = 0; mf < 2; ++mf)
                #pragma unroll
                for (int r = 0; r < 4; ++r) {
                    float u = a1[mf][nf][r] + bias;
                    float t = 1.5957691216057308f * (u + 0.044715f * u * u * u);
                    float ge = u * __builtin_amdgcn_rcpf(1.0f + __expf(-t));
                    gl[(wm * 32 + mf * 16 + kh * 4 + r) * 104 + lcol] = f2bf(ge);
                }
        }
        __syncthreads();
        #pragma unroll
        for (int kc = 0; kc < 3; ++kc) {
            int k0 = kc * 32;
            bf16x8 ag[2];
            #pragma unroll
            for (int mf = 0; mf < 2; ++mf)
                ag[mf] = *(const bf16x8*)&gl[(wm * 32 + mf * 16 + lr) * 104 + k0 + kh * 8];
            #pragma unroll
            for (int nf = 0; nf < 3; ++nf) {
                bf16x8 bb = *(const bf16x8*)(w2_t + (size_t)(wn * 48 + nf * 16 + lr) * 384 + ch * 96 + k0 + kh * 8);
                #pragma unroll
                for (int mf = 0; mf < 2; ++mf)
                    acc2[mf][nf] = __builtin_amdgcn_mfma_f32_16x16x32_bf16(ag[mf], bb, acc2[mf][nf], 0, 0, 0);
            }
        }
        __syncthreads();
    }

    // ---- Output staging + coalesced flush ----
    #pragma unroll
    for (int r = 0; r < 4; ++r) {
        int t = tb + kh * 4 + r;
        #pragma unroll
        for (int n = 0; n < 6; ++n)
            tile[t * 100 + n * 16 + lr] = x1v[n][r];
    }
    __syncthreads();
    #pragma unroll
    for (int nf = 0; nf < 3; ++nf) {
        int col = wn * 48 + nf * 16 + lr;
        float bc = b2[col];
        #pragma unroll
        for (int mf = 0; mf < 2; ++mf)
            #pragma unroll
            for (int r = 0; r < 4; ++r) {
                int row = wm * 32 + mf * 16 + kh * 4 + r;
                tile[row * 100 + col] += acc2[mf][nf][r] + bc;
            }
    }
    __syncthreads();
    #pragma unroll
    for (int j = 0; j < 6; ++j) {
        int f4 = j * 256 + tid;
        int token = f4 / 24, c4 = f4 % 24;
        int wx = token >> 4, wy = (token >> 2) & 3, wz = token & 3;
        int qx = (ix * 4 + wx + 2) & 63, qy = (iy * 4 + wy + 2) & 63, qz = (iz * 4 + wz + 2) & 63;
        size_t g = ((size_t)((qx * 64 + qy) * 64 + qz)) * 96 + c4 * 4;
        f32x4 v = *(const f32x4*)&tile[token * 100 + c4 * 4];
        *(f32x4*)&out[g] = v;
    }
}

extern "C" void kernel_launch(void* const* d_in, const int* in_sizes, int n_in,
                              void* d_out, int out_size, void* d_ws, size_t ws_size,
                              hipStream_t stream) {
    const float* x       = (const float*)d_in[0];
    const float* Wqkv    = (const float*)d_in[1];
    const float* Wout    = (const float*)d_in[2];
    const float* b_out   = (const float*)d_in[3];
    const float* pos_tab = (const float*)d_in[4];
    const float* ln1_g   = (const float*)d_in[5];
    const float* ln1_b   = (const float*)d_in[6];
    const float* ln2_g   = (const float*)d_in[7];
    const float* ln2_b   = (const float*)d_in[8];
    const float* W1      = (const float*)d_in[9];
    const float* b1      = (const float*)d_in[10];
    const float* W2      = (const float*)d_in[11];
    const float* b2      = (const float*)d_in[12];
    float* out = (float*)d_out;

    char* ws = (char*)d_ws;
    unsigned short* a_out = (unsigned short*)(ws);              // 48 MB (attention output)
    unsigned short* wq_t  = (unsigned short*)(ws + 50331648);   // 55296 B
    unsigned short* wo_t  = wq_t + 27648;                       // 18432 B
    unsigned short* w1_t  = wo_t + 9216;                        // 73728 B
    unsigned short* w2_t  = w1_t + 36864;                       // 73728 B

    convert_weights<<<432, 256, 0, stream>>>(Wqkv, Wout, W1, W2, wq_t, wo_t, w1_t, w2_t);
    ln_qkv_attn_kernel<<<NWIN, 384, 0, stream>>>(x, ln1_g, ln1_b, wq_t, pos_tab, a_out);
    proj_mlp5_kernel<<<NWIN, 256, 0, stream>>>(a_out, wo_t, b_out, x,
                                               ln2_g, ln2_b, w1_t, b1, w2_t, b2, out);
}

// Round 11
// 231.430 us; speedup vs baseline: 1.7328x; 1.0087x over previous
//
#include <hip/hip_runtime.h>
#include <hip/hip_bf16.h>

typedef __attribute__((ext_vector_type(8))) short bf16x8;
typedef __attribute__((ext_vector_type(4))) short s16x4;
typedef __attribute__((ext_vector_type(4))) float f32x4;

#define NWIN 4096     // 16^3 windows of 4^3

// native bf16 convert (RNE) -> single v_cvt instruction on gfx950
__device__ __forceinline__ unsigned short f2bf(float f) {
    __hip_bfloat16 h = __float2bfloat16(f);
    unsigned short u;
    __builtin_memcpy(&u, &h, 2);
    return u;
}
__device__ __forceinline__ float bf2f(unsigned short u) {
    return __uint_as_float(((unsigned int)u) << 16);
}
__device__ __forceinline__ int region(int g) { return (g >= 60) + (g >= 62); }

// ---------------- K0: weight convert + transpose to N-major bf16 ----------------
__global__ void convert_weights(const float* __restrict__ Wqkv, const float* __restrict__ Wout,
                                const float* __restrict__ W1, const float* __restrict__ W2,
                                unsigned short* __restrict__ wq_t, unsigned short* __restrict__ wo_t,
                                unsigned short* __restrict__ w1_t, unsigned short* __restrict__ w2_t) {
    int idx = blockIdx.x * blockDim.x + threadIdx.x;
    if (idx < 27648) {                       // wq_t[288][96] = Wqkv[96][288]^T
        int n = idx / 96, k = idx % 96;
        wq_t[idx] = f2bf(Wqkv[k * 288 + n]);
    } else if (idx < 27648 + 9216) {         // wo_t[96][96]
        int i = idx - 27648; int n = i / 96, k = i % 96;
        wo_t[i] = f2bf(Wout[k * 96 + n]);
    } else if (idx < 27648 + 9216 + 36864) { // w1_t[384][96]
        int i = idx - 36864; int n = i / 96, k = i % 96;
        w1_t[i] = f2bf(W1[k * 384 + n]);
    } else if (idx < 110592) {               // w2_t[96][384]
        int i = idx - 73728; int n = i / 384, k = i % 384;
        w2_t[i] = f2bf(W2[k * 96 + n]);
    }
}

// ---------------- K1: FUSED LN1 + QKV GEMM + attention (one window, 6 waves) ----------------
// LDS: q[3][64][40] (7680 sh) + k[3][64][40] (7680 sh) + vT[3][32][72] (6912 sh) = 22272 sh.
// y_s [64][104] (6656 sh) ALIASES the vT region (y dead after GEMM reads; vT written after
// the post-GEMM barrier). P[3][64][72] aliases q+k after S2. LDS 44.5KB -> 3 blocks/CU.
__global__ __launch_bounds__(384, 4) void ln_qkv_attn_kernel(
    const float* __restrict__ x,
    const float* __restrict__ ln1_g, const float* __restrict__ ln1_b,
    const unsigned short* __restrict__ wq_t,
    const float* __restrict__ pos_tab,
    unsigned short* __restrict__ a_out)
{
    __shared__ __align__(16) unsigned short SH[22272];
    __shared__ __align__(16) float posl[344];
    unsigned short* q_s = SH;             // [3][64][40]
    unsigned short* k_s = SH + 7680;      // [3][64][40]
    unsigned short* vT  = SH + 15360;     // [3][32][72]
    unsigned short* y_s = SH + 15360;     // [64][104]  (aliases vT; dead before vT written)
    unsigned short* P_s = SH;             // [3][64][72] (aliases q+k after S2)

    int win = blockIdx.x;
    int tid = threadIdx.x;
    int w = tid >> 6, lane = tid & 63, lr = lane & 15, kh = lane >> 4;
    int ix = win >> 8, iy = (win >> 4) & 15, iz = win & 15;

    if (tid < 343) posl[tid] = pos_tab[tid];

    // ---- P0: LN1 on shifted-gathered window tokens -> y_s (bf16) ----
    {
        int grp = tid >> 4, gi = tid & 15;   // 24 groups of 16 lanes
        float gv[6], bv[6];
        #pragma unroll
        for (int j = 0; j < 6; ++j) { gv[j] = ln1_g[gi + 16 * j]; bv[j] = ln1_b[gi + 16 * j]; }
        #pragma unroll
        for (int p = 0; p < 3; ++p) {
            int t = grp + p * 24;
            if (t < 64) {
                int wx = t >> 4, wy = (t >> 2) & 3, wz = t & 3;
                int sx = (ix * 4 + wx + 2) & 63, sy = (iy * 4 + wy + 2) & 63, sz = (iz * 4 + wz + 2) & 63;
                const float* src = x + ((size_t)((sx * 64 + sy) * 64 + sz)) * 96;
                float v[6]; float s = 0.f, sq = 0.f;
                #pragma unroll
                for (int j = 0; j < 6; ++j) { v[j] = src[gi + 16 * j]; s += v[j]; sq += v[j] * v[j]; }
                #pragma unroll
                for (int m = 8; m >= 1; m >>= 1) { s += __shfl_xor(s, m, 16); sq += __shfl_xor(sq, m, 16); }
                float mean = s * (1.0f / 96.0f);
                float var = sq * (1.0f / 96.0f) - mean * mean;
                float rstd = rsqrtf(var + 1e-5f);
                #pragma unroll
                for (int j = 0; j < 6; ++j)
                    y_s[t * 104 + gi + 16 * j] = f2bf((v[j] - mean) * rstd * gv[j] + bv[j]);
            }
        }
    }
    __syncthreads();   // y_s visible

    // ---- P1: QKV GEMM (A = y_s from LDS, B = wq_t from L2) ----
    f32x4 acc3[4][3];
    {
        #pragma unroll
        for (int m = 0; m < 4; ++m)
            #pragma unroll
            for (int n = 0; n < 3; ++n) acc3[m][n] = (f32x4){0.f, 0.f, 0.f, 0.f};
        #pragma unroll
        for (int ks = 0; ks < 3; ++ks) {
            int k0 = ks * 32;
            bf16x8 a[4], bb[3];
            #pragma unroll
            for (int m = 0; m < 4; ++m)
                a[m] = *(const bf16x8*)&y_s[(m * 16 + lr) * 104 + k0 + kh * 8];
            #pragma unroll
            for (int n = 0; n < 3; ++n)
                bb[n] = *(const bf16x8*)(wq_t + (size_t)(w * 48 + n * 16 + lr) * 96 + k0 + kh * 8);
            #pragma unroll
            for (int m = 0; m < 4; ++m)
                #pragma unroll
                for (int n = 0; n < 3; ++n)
                    acc3[m][n] = __builtin_amdgcn_mfma_f32_16x16x32_bf16(a[m], bb[n], acc3[m][n], 0, 0, 0);
        }
    }
    __syncthreads();   // all y_s reads complete -> safe to overwrite vT region

    // ---- scatter to q_s (pre-scaled) / k_s / vT ----
    {
        const float scale = 0.17677669529663689f;   // 32^-0.5 folded into Q
        #pragma unroll
        for (int n = 0; n < 3; ++n) {
            int base = w * 48 + n * 16;
            int qq = base / 96, cc0 = base % 96;
            int hh = cc0 >> 5, d0 = cc0 & 31;
            if (qq == 2) {
                #pragma unroll
                for (int m = 0; m < 4; ++m) {
                    s16x4 pv;
                    #pragma unroll
                    for (int r = 0; r < 4; ++r) pv[r] = (short)f2bf(acc3[m][n][r]);
                    *(s16x4*)&vT[(hh * 32 + d0 + lr) * 72 + m * 16 + kh * 4] = pv;
                }
            } else {
                unsigned short* dst = (qq == 0) ? q_s : k_s;
                float sc = (qq == 0) ? scale : 1.0f;
                #pragma unroll
                for (int m = 0; m < 4; ++m)
                    #pragma unroll
                    for (int r = 0; r < 4; ++r) {
                        int tok = m * 16 + kh * 4 + r;
                        dst[(hh * 64 + tok) * 40 + d0 + lr] = f2bf(acc3[m][n][r] * sc);
                    }
            }
        }
    }
    __syncthreads();   // S1: q/k/vT + posl visible

    // ---- P2: QK^T + bias + mask + softmax (2 waves per head) ----
    int h3 = w >> 1, rb = (w & 1) * 32;
    f32x4 sa[2][4];
    {
        bf16x8 aq[2], bk[4];
        #pragma unroll
        for (int mm = 0; mm < 2; ++mm)
            aq[mm] = *(const bf16x8*)&q_s[(h3 * 64 + rb + mm * 16 + lr) * 40 + kh * 8];
        #pragma unroll
        for (int n = 0; n < 4; ++n)
            bk[n] = *(const bf16x8*)&k_s[(h3 * 64 + n * 16 + lr) * 40 + kh * 8];
        #pragma unroll
        for (int mm = 0; mm < 2; ++mm)
            #pragma unroll
            for (int n = 0; n < 4; ++n)
                sa[mm][n] = __builtin_amdgcn_mfma_f32_16x16x32_bf16(aq[mm], bk[n], (f32x4){0.f,0.f,0.f,0.f}, 0, 0, 0);

        int labj[4], jwx[4], jwy[4], jwz[4];
        #pragma unroll
        for (int n = 0; n < 4; ++n) {
            int j = n * 16 + lr;
            jwx[n] = j >> 4; jwy[n] = (j >> 2) & 3; jwz[n] = j & 3;
            labj[n] = 9 * region(ix * 4 + jwx[n]) + 3 * region(iy * 4 + jwy[n]) + region(iz * 4 + jwz[n]);
        }
        #pragma unroll
        for (int mm = 0; mm < 2; ++mm)
            #pragma unroll
            for (int r = 0; r < 4; ++r) {
                int i = rb + mm * 16 + kh * 4 + r;
                int iwx = i >> 4, iwy = (i >> 2) & 3, iwz = i & 3;
                int labi = 9 * region(ix * 4 + iwx) + 3 * region(iy * 4 + iwy) + region(iz * 4 + iwz);
                #pragma unroll
                for (int n = 0; n < 4; ++n) {
                    float bias = posl[((iwx - jwx[n] + 3) * 7 + (iwy - jwy[n] + 3)) * 7 + (iwz - jwz[n] + 3)];
                    sa[mm][n][r] += bias + (labi != labj[n] ? -1e9f : 0.0f);
                }
                float mx = fmaxf(fmaxf(sa[mm][0][r], sa[mm][1][r]), fmaxf(sa[mm][2][r], sa[mm][3][r]));
                #pragma unroll
                for (int s = 1; s < 16; s <<= 1) mx = fmaxf(mx, __shfl_xor(mx, s, 16));
                float e0 = __expf(sa[mm][0][r] - mx), e1 = __expf(sa[mm][1][r] - mx);
                float e2 = __expf(sa[mm][2][r] - mx), e3 = __expf(sa[mm][3][r] - mx);
                float sum = e0 + e1 + e2 + e3;
                #pragma unroll
                for (int s = 1; s < 16; s <<= 1) sum += __shfl_xor(sum, s, 16);
                float rs = 1.0f / sum;
                sa[mm][0][r] = e0 * rs; sa[mm][1][r] = e1 * rs;
                sa[mm][2][r] = e2 * rs; sa[mm][3][r] = e3 * rs;
            }
    }
    __syncthreads();   // S2: all q/k reads complete -> safe to overwrite with P

    // write P (bf16) over q/k region
    #pragma unroll
    for (int mm = 0; mm < 2; ++mm)
        #pragma unroll
        for (int n = 0; n < 4; ++n)
            #pragma unroll
            for (int r = 0; r < 4; ++r)
                P_s[(h3 * 64 + rb + mm * 16 + kh * 4 + r) * 72 + n * 16 + lr] = f2bf(sa[mm][n][r]);
    __syncthreads();   // S3: P visible

    // ---- P3: PV + write a_out ----
    {
        f32x4 oa[2][2];
        #pragma unroll
        for (int mm = 0; mm < 2; ++mm)
            #pragma unroll
            for (int n = 0; n < 2; ++n) oa[mm][n] = (f32x4){0.f, 0.f, 0.f, 0.f};
        #pragma unroll
        for (int ks = 0; ks < 2; ++ks) {
            int k0 = ks * 32;
            bf16x8 ap[2], bv[2];
            #pragma unroll
            for (int mm = 0; mm < 2; ++mm)
                ap[mm] = *(const bf16x8*)&P_s[(h3 * 64 + rb + mm * 16 + lr) * 72 + k0 + kh * 8];
            #pragma unroll
            for (int n = 0; n < 2; ++n)
                bv[n] = *(const bf16x8*)&vT[(h3 * 32 + n * 16 + lr) * 72 + k0 + kh * 8];
            #pragma unroll
            for (int mm = 0; mm < 2; ++mm)
                #pragma unroll
                for (int n = 0; n < 2; ++n)
                    oa[mm][n] = __builtin_amdgcn_mfma_f32_16x16x32_bf16(ap[mm], bv[n], oa[mm][n], 0, 0, 0);
        }
        #pragma unroll
        for (int mm = 0; mm < 2; ++mm)
            #pragma unroll
            for (int n = 0; n < 2; ++n)
                #pragma unroll
                for (int r = 0; r < 4; ++r) {
                    int tok = rb + mm * 16 + kh * 4 + r;
                    a_out[((size_t)win * 64 + tok) * 96 + h3 * 32 + n * 16 + lr] = f2bf(oa[mm][n][r]);
                }
    }
}

// ---------------- K2: proj + residual + LN2 + MLP + residual (round-9 structure) ----------------
__global__ __launch_bounds__(256, 4) void proj_mlp5_kernel(
    const unsigned short* __restrict__ a_out,
    const unsigned short* __restrict__ wo_t, const float* __restrict__ b_out,
    const float* __restrict__ x,
    const float* __restrict__ g2, const float* __restrict__ bt2,
    const unsigned short* __restrict__ w1_t, const float* __restrict__ b1,
    const unsigned short* __restrict__ w2_t, const float* __restrict__ b2,
    float* __restrict__ out)
{
    __shared__ __align__(16) unsigned short SH[13312];   // xl @0, gl @6656; tile overlays all
    unsigned short* xl = SH;          // [64][104] bf16
    unsigned short* gl = SH + 6656;   // [64][104] bf16
    float* tile = (float*)SH;         // [64][100] f32 (25.6 KB <= 26.6 KB)

    int win = blockIdx.x;
    int tid = threadIdx.x;
    int w = tid >> 6, lane = tid & 63, lr = lane & 15, kh = lane >> 4;
    int ix = win >> 8, iy = (win >> 4) & 15, iz = win & 15;
    int tb = w * 16;

    int px = (ix * 4 + w + 2) & 63;
    int py = (iy * 4 + kh + 2) & 63;
    int rowbase = (px * 64 + py) * 64;
    int o[4];
    #pragma unroll
    for (int r = 0; r < 4; ++r) o[r] = (rowbase + ((iz * 4 + r + 2) & 63)) * 96;

    // ---- Phase A: proj GEMM (M=16/wave) + x residual + in-register LN2 -> xl ----
    float x1v[6][4];
    {
        f32x4 pa[6];
        #pragma unroll
        for (int n = 0; n < 6; ++n) pa[n] = (f32x4){0.f, 0.f, 0.f, 0.f};
        #pragma unroll
        for (int ks = 0; ks < 3; ++ks) {
            int k0 = ks * 32;
            bf16x8 a = *(const bf16x8*)(a_out + ((size_t)win * 64 + tb + lr) * 96 + k0 + kh * 8);
            #pragma unroll
            for (int n = 0; n < 6; ++n) {
                bf16x8 bb = *(const bf16x8*)(wo_t + (size_t)(n * 16 + lr) * 96 + k0 + kh * 8);
                pa[n] = __builtin_amdgcn_mfma_f32_16x16x32_bf16(a, bb, pa[n], 0, 0, 0);
            }
        }
        #pragma unroll
        for (int n = 0; n < 6; ++n) {
            int c = n * 16 + lr;
            float bo = b_out[c];
            #pragma unroll
            for (int r = 0; r < 4; ++r)
                x1v[n][r] = x[o[r] + c] + pa[n][r] + bo;
        }
        float g2c[6], bc2[6];
        #pragma unroll
        for (int n = 0; n < 6; ++n) { g2c[n] = g2[n * 16 + lr]; bc2[n] = bt2[n * 16 + lr]; }
        #pragma unroll
        for (int r = 0; r < 4; ++r) {
            float s = 0.f, sq = 0.f;
            #pragma unroll
            for (int n = 0; n < 6; ++n) { s += x1v[n][r]; sq += x1v[n][r] * x1v[n][r]; }
            #pragma unroll
            for (int m = 8; m >= 1; m >>= 1) { s += __shfl_xor(s, m, 16); sq += __shfl_xor(sq, m, 16); }
            float mean = s * (1.0f / 96.0f);
            float var = sq * (1.0f / 96.0f) - mean * mean;
            float rstd = rsqrtf(var + 1e-5f);
            int t = tb + kh * 4 + r;
            #pragma unroll
            for (int n = 0; n < 6; ++n)
                xl[t * 104 + n * 16 + lr] = f2bf((x1v[n][r] - mean) * rstd * g2c[n] + bc2[n]);
        }
    }
    __syncthreads();

    // ---- MLP: 4 hidden chunks of 96; wave grid wm(2 M-bands) x wn(2 N-bands of 48) ----
    int wm = w & 1, wn = w >> 1;
    f32x4 acc2[2][3];
    #pragma unroll
    for (int mf = 0; mf < 2; ++mf)
        #pragma unroll
        for (int nf = 0; nf < 3; ++nf) acc2[mf][nf] = (f32x4){0.f, 0.f, 0.f, 0.f};

    for (int ch = 0; ch < 4; ++ch) {
        f32x4 a1[2][3];
        #pragma unroll
        for (int mf = 0; mf < 2; ++mf)
            #pragma unroll
            for (int nf = 0; nf < 3; ++nf) a1[mf][nf] = (f32x4){0.f, 0.f, 0.f, 0.f};
        #pragma unroll
        for (int ks = 0; ks < 3; ++ks) {
            int k0 = ks * 32;
            bf16x8 af[2], bfr[3];
            #pragma unroll
            for (int mf = 0; mf < 2; ++mf)
                af[mf] = *(const bf16x8*)&xl[(wm * 32 + mf * 16 + lr) * 104 + k0 + kh * 8];
            #pragma unroll
            for (int nf = 0; nf < 3; ++nf)
                bfr[nf] = *(const bf16x8*)(w1_t + (size_t)(ch * 96 + wn * 48 + nf * 16 + lr) * 96 + k0 + kh * 8);
            #pragma unroll
            for (int mf = 0; mf < 2; ++mf)
                #pragma unroll
                for (int nf = 0; nf < 3; ++nf)
                    a1[mf][nf] = __builtin_amdgcn_mfma_f32_16x16x32_bf16(af[mf], bfr[nf], a1[mf][nf], 0, 0, 0);
        }
        #pragma unroll
        for (int nf = 0; nf < 3; ++nf) {
            int lcol = wn * 48 + nf * 16 + lr;
            float bias = b1[ch * 96 + lcol];
            #pragma unroll
            for (int mf = 0; mf < 2; ++mf)
                #pragma unroll
                for (int r = 0; r < 4; ++r) {
                    float u = a1[mf][nf][r] + bias;
                    float t = 1.5957691216057308f * (u + 0.044715f * u * u * u);
                    float ge = u * __builtin_amdgcn_rcpf(1.0f + __expf(-t));
                    gl[(wm * 32 + mf * 16 + kh * 4 + r) * 104 + lcol] = f2bf(ge);
                }
        }
        __syncthreads();
        #pragma unroll
        for (int kc = 0; kc < 3; ++kc) {
            int k0 = kc * 32;
            bf16x8 ag[2];
            #pragma unroll
            for (int mf = 0; mf < 2; ++mf)
                ag[mf] = *(const bf16x8*)&gl[(wm * 32 + mf * 16 + lr) * 104 + k0 + kh * 8];
            #pragma unroll
            for (int nf = 0; nf < 3; ++nf) {
                bf16x8 bb = *(const bf16x8*)(w2_t + (size_t)(wn * 48 + nf * 16 + lr) * 384 + ch * 96 + k0 + kh * 8);
                #pragma unroll
                for (int mf = 0; mf < 2; ++mf)
                    acc2[mf][nf] = __builtin_amdgcn_mfma_f32_16x16x32_bf16(ag[mf], bb, acc2[mf][nf], 0, 0, 0);
            }
        }
        __syncthreads();
    }

    // ---- Output staging + coalesced flush ----
    #pragma unroll
    for (int r = 0; r < 4; ++r) {
        int t = tb + kh * 4 + r;
        #pragma unroll
        for (int n = 0; n < 6; ++n)
            tile[t * 100 + n * 16 + lr] = x1v[n][r];
    }
    __syncthreads();
    #pragma unroll
    for (int nf = 0; nf < 3; ++nf) {
        int col = wn * 48 + nf * 16 + lr;
        float bc = b2[col];
        #pragma unroll
        for (int mf = 0; mf < 2; ++mf)
            #pragma unroll
            for (int r = 0; r < 4; ++r) {
                int row = wm * 32 + mf * 16 + kh * 4 + r;
                tile[row * 100 + col] += acc2[mf][nf][r] + bc;
            }
    }
    __syncthreads();
    #pragma unroll
    for (int j = 0; j < 6; ++j) {
        int f4 = j * 256 + tid;
        int token = f4 / 24, c4 = f4 % 24;
        int wx = token >> 4, wy = (token >> 2) & 3, wz = token & 3;
        int qx = (ix * 4 + wx + 2) & 63, qy = (iy * 4 + wy + 2) & 63, qz = (iz * 4 + wz + 2) & 63;
        size_t g = ((size_t)((qx * 64 + qy) * 64 + qz)) * 96 + c4 * 4;
        f32x4 v = *(const f32x4*)&tile[token * 100 + c4 * 4];
        *(f32x4*)&out[g] = v;
    }
}

extern "C" void kernel_launch(void* const* d_in, const int* in_sizes, int n_in,
                              void* d_out, int out_size, void* d_ws, size_t ws_size,
                              hipStream_t stream) {
    const float* x       = (const float*)d_in[0];
    const float* Wqkv    = (const float*)d_in[1];
    const float* Wout    = (const float*)d_in[2];
    const float* b_out   = (const float*)d_in[3];
    const float* pos_tab = (const float*)d_in[4];
    const float* ln1_g   = (const float*)d_in[5];
    const float* ln1_b   = (const float*)d_in[6];
    const float* ln2_g   = (const float*)d_in[7];
    const float* ln2_b   = (const float*)d_in[8];
    const float* W1      = (const float*)d_in[9];
    const float* b1      = (const float*)d_in[10];
    const float* W2      = (const float*)d_in[11];
    const float* b2      = (const float*)d_in[12];
    float* out = (float*)d_out;

    char* ws = (char*)d_ws;
    unsigned short* a_out = (unsigned short*)(ws);              // 48 MB (attention output)
    unsigned short* wq_t  = (unsigned short*)(ws + 50331648);   // 55296 B
    unsigned short* wo_t  = wq_t + 27648;                       // 18432 B
    unsigned short* w1_t  = wo_t + 9216;                        // 73728 B
    unsigned short* w2_t  = w1_t + 36864;                       // 73728 B

    convert_weights<<<432, 256, 0, stream>>>(Wqkv, Wout, W1, W2, wq_t, wo_t, w1_t, w2_t);
    ln_qkv_attn_kernel<<<NWIN, 384, 0, stream>>>(x, ln1_g, ln1_b, wq_t, pos_tab, a_out);
    proj_mlp5_kernel<<<NWIN, 256, 0, stream>>>(a_out, wo_t, b_out, x,
                                               ln2_g, ln2_b, w1_t, b1, w2_t, b2, out);
}